// Round 8
// baseline (468.200 us; speedup 1.0000x reference)
//
#include <hip/hip_runtime.h>
#include <hip/hip_fp16.h>
#include <math.h>

// SPAIRPointFeatureNetwork on MI355X.
//   h_{p,j} = Q[j] - G[p];  celu monotonic => segmax(celu(h)) = celu(max_j Q[j] - G[p]).
//
// R7 post-mortem: the 3 edge/layer kernels are ~35us each, invariant to
// coalescing/sort/MLP => per-edge L1-miss (miss-queue x L2-latency) bound.
// R8: block = one grid cell; stage the cell's 27-neighborhood Q rows into LDS
// once (contiguous streams from the cell-sorted table), edges read LDS via
// precomputed u16 neighborhood-local slots. Misses: 4.19M random -> ~1.8M
// sequential. Overflow beyond the LDS cap reads global (correct, ~never hit).

#define NPTS 65536
#define KNBR 64
#define GRES 16
#define NCELL 4096   // 16^3

__device__ __forceinline__ float celu1(float x) {
    return x > 0.0f ? x : (__expf(x) - 1.0f);
}

__device__ __forceinline__ unsigned pkmax(unsigned a, unsigned b) {
    unsigned d;
    asm("v_pk_max_f16 %0, %1, %2" : "=v"(d) : "v"(a), "v"(b));
    return d;
}

__device__ __forceinline__ unsigned pack2(float a, float b) {
    __half2 h = __floats2half2_rn(a, b);
    return *(unsigned*)&h;
}

__device__ __forceinline__ int cell_of(float p0, float p1, float p2) {
    // exact match with reference: p/R = p*16 exact in fp32 and fp64
    int cx = min((int)(p0 * 16.0f), 15);
    int cy = min((int)(p1 * 16.0f), 15);
    int cz = min((int)(p2 * 16.0f), 15);
    return (cx * GRES + cy) * GRES + cz;
}

// Build this cell's 27-neighbor descriptor (lex order over dx,dy,dz):
// s_start[r] = sorted start of neighbor cell r, s_pfx[r] = exclusive prefix of
// counts (LDS slot base), s_pfx[27] = total rows. First wave only; caller syncs.
__device__ __forceinline__ void build_desc(
    int cid, const int* __restrict__ starts, const int* __restrict__ counts,
    int* s_start, int* s_pfx)
{
    if (threadIdx.x < 64) {
        int lane = threadIdx.x;
        int cnt = 0, st = 0;
        if (lane < 27) {
            int cx = cid >> 8, cy = (cid >> 4) & 15, cz = cid & 15;
            int dx = lane / 9 - 1, dy = (lane / 3) % 3 - 1, dz = lane % 3 - 1;
            int nx = cx + dx, ny = cy + dy, nz = cz + dz;
            bool ok = ((unsigned)nx < 16u) && ((unsigned)ny < 16u) && ((unsigned)nz < 16u);
            if (ok) {
                int nc = (((nx << 4) | ny) << 4) | nz;
                cnt = counts[nc];
                st  = starts[nc];
            }
        }
        int inc = cnt;
#pragma unroll
        for (int d = 1; d < 32; d <<= 1) {
            int u = __shfl_up(inc, d, 64);
            if (lane >= d) inc += u;
        }
        if (lane < 27) { s_start[lane] = st; s_pfx[lane] = inc - cnt; }
        if (lane == 26) s_pfx[27] = inc;
    }
}

// ---- sort pipeline ----

__global__ __launch_bounds__(256) void k_zero(int* __restrict__ buf) {
    buf[blockIdx.x * 256 + threadIdx.x] = 0;   // counts + cursor
}

__global__ __launch_bounds__(256) void k_hist(
    const float* __restrict__ pos, int* __restrict__ counts)
{
    int t = blockIdx.x * 256 + threadIdx.x;
    if (t >= NPTS) return;
    int cid = cell_of(pos[3 * t], pos[3 * t + 1], pos[3 * t + 2]);
    atomicAdd(&counts[cid], 1);
}

// single wave: exclusive scan of 4096 counts -> starts
__global__ void k_scan(const int* __restrict__ counts, int* __restrict__ starts) {
    int lane = threadIdx.x;             // 0..63, 64 cells each
    const int4* cp = (const int4*)counts;
    int4 c[16];
#pragma unroll
    for (int k = 0; k < 16; ++k) c[k] = cp[lane * 16 + k];
    int T = 0;
#pragma unroll
    for (int k = 0; k < 16; ++k) T += c[k].x + c[k].y + c[k].z + c[k].w;
    int inc = T;
#pragma unroll
    for (int d = 1; d < 64; d <<= 1) {
        int u = __shfl_up(inc, d, 64);
        if (lane >= d) inc += u;
    }
    int run = inc - T;
    int4* sp = (int4*)starts;
#pragma unroll
    for (int k = 0; k < 16; ++k) {
        int4 v = c[k], o;
        o.x = run; run += v.x;
        o.y = run; run += v.y;
        o.z = run; run += v.z;
        o.w = run; run += v.w;
        sp[lane * 16 + k] = o;
    }
}

// slot assignment + sorted pos + cell id + sorted Q1 + d_out pos/batch
__global__ __launch_bounds__(256) void k_slot(
    const float* __restrict__ pos,
    const int* __restrict__ starts, int* __restrict__ cursor,
    int* __restrict__ slot_of, int* __restrict__ perm,
    unsigned short* __restrict__ cell16,
    float* __restrict__ pos_s,
    const float* __restrict__ w1a, const float* __restrict__ b1a,
    __half* __restrict__ q1,
    float* __restrict__ dout, int out_size)
{
    int t = blockIdx.x * 256 + threadIdx.x;
    if (t >= NPTS) return;
    float p0 = pos[3 * t + 0];
    float p1 = pos[3 * t + 1];
    float p2 = pos[3 * t + 2];
    dout[3 * t + 0] = p0;
    dout[3 * t + 1] = p1;
    dout[3 * t + 2] = p2;
    for (int j = 35 * NPTS + t; j < out_size; j += NPTS)
        dout[j] = 0.0f;

    int cid = cell_of(p0, p1, p2);
    int s = starts[cid] + atomicAdd(&cursor[cid], 1);
    slot_of[t] = s;
    perm[s] = t;
    cell16[s] = (unsigned short)cid;
    pos_s[3 * s + 0] = p0;
    pos_s[3 * s + 1] = p1;
    pos_s[3 * s + 2] = p2;

    float q[8];
#pragma unroll
    for (int c = 0; c < 8; ++c) {
        float a = b1a[c];
        a = fmaf(p0, w1a[0 * 8 + c] + w1a[3 * 8 + c], a);
        a = fmaf(p1, w1a[1 * 8 + c] + w1a[4 * 8 + c], a);
        a = fmaf(p2, w1a[2 * 8 + c] + w1a[5 * 8 + c], a);
        q[c] = a;
    }
    uint4 pk;
    pk.x = pack2(q[0], q[1]);
    pk.y = pack2(q[2], q[3]);
    pk.z = pack2(q[4], q[5]);
    pk.w = pack2(q[6], q[7]);
    *(uint4*)(q1 + 8 * s) = pk;
}

// remap edges to neighborhood-local LDS slots (u16); one block per cell.
// slot computed O(1) from the neighbor's cell id (no search).
__global__ __launch_bounds__(256) void k_remap(
    const int* __restrict__ idx,       // original N x 64
    const int* __restrict__ perm,
    const int* __restrict__ slot_of,
    const unsigned short* __restrict__ cell16,
    const int* __restrict__ starts,
    const int* __restrict__ counts,
    unsigned short* __restrict__ es)   // sorted N x 64, slot per edge
{
    __shared__ int s_start[27];
    __shared__ int s_pfx[28];
    int cid = blockIdx.x;
    build_desc(cid, starts, counts, s_start, s_pfx);
    __syncthreads();

    int base = starts[cid];
    int P = counts[cid];
    int cx = cid >> 8, cy = (cid >> 4) & 15, cz = cid & 15;
    int tasks = P * 64;
    for (int task = threadIdx.x; task < tasks; task += 256) {
        int p_s = base + (task >> 6);
        int e = task & 63;
        int orig = perm[p_s];
        int j_orig = idx[orig * 64 + e];
        int j_s = slot_of[j_orig];
        int jc = cell16[j_s];
        int r = ((jc >> 8) - cx + 1) * 9 + (((jc >> 4) & 15) - cy + 1) * 3 + ((jc & 15) - cz + 1);
        int slot = s_pfx[r] + (j_s - s_start[r]);
        es[p_s * 64 + e] = (unsigned short)slot;
    }
}

// ---- fused layer: stage neighborhood in LDS -> edge max -> finish ----
// Block = one cell, 256 threads (4 waves). Per point: lane = ep*SL + c,
// c = 16B slice (SL per row), ep = edge sub-index; SL passes cover 64 edges.
template <int FH, int FOUT, int FHN, bool WRITEX, int SCAP>
__global__ __launch_bounds__(256) void k_layer(
    const __half* __restrict__ q,    // sorted N x FH
    const unsigned short* __restrict__ es,
    const float* __restrict__ pos_s,
    const int* __restrict__ starts,
    const int* __restrict__ counts,
    const int* __restrict__ perm,
    const float* __restrict__ wap,   // 3 x FH (dpos rows of this layer's wa)
    const float* __restrict__ wb,    // FH x FOUT
    const float* __restrict__ bb,    // FOUT
    const float* __restrict__ wan,   // (FOUT+3) x FHN or null
    const float* __restrict__ ban,   // FHN or null
    float* __restrict__ xout,        // x region base (WRITEX only)
    __half* __restrict__ qnext)      // sorted N x FHN (FHN>0 only)
{
    constexpr int SL  = FH / 8;      // 16B slices per row (1,2,4)
    constexpr int EPP = 64 / SL;     // edges per pass

    __shared__ int s_start[27];
    __shared__ int s_pfx[28];
    __shared__ uint4 rows[SCAP * SL];
    __shared__ uint4 m_lds[128 * SL];

    int cid = blockIdx.x;
    build_desc(cid, starts, counts, s_start, s_pfx);
    __syncthreads();

    int total = s_pfx[27];
    int stot = min(total, SCAP);
    // stage neighborhood rows (contiguous per range -> coalesced streams)
    for (int s = threadIdx.x; s < stot; s += 256) {
        int r = 0;
        while (s >= s_pfx[r + 1]) ++r;
        int row_g = s_start[r] + (s - s_pfx[r]);
        const uint4* src = (const uint4*)(q + row_g * FH);
#pragma unroll
        for (int k = 0; k < SL; ++k) rows[s * SL + k] = src[k];
    }
    __syncthreads();

    int base = starts[cid];
    int P = counts[cid];
    int w = threadIdx.x >> 6;
    int l = threadIdx.x & 63;
    int c  = l % SL;
    int ep = l / SL;

    for (int pl = w; pl < P; pl += 4) {
        int p = base + pl;
        int sv[SL];
#pragma unroll
        for (int pass = 0; pass < SL; ++pass)
            sv[pass] = es[p * 64 + pass * EPP + ep];
        unsigned ax = 0xFC00FC00u, ay = 0xFC00FC00u, az = 0xFC00FC00u, aw = 0xFC00FC00u;
#pragma unroll
        for (int pass = 0; pass < SL; ++pass) {
            int s = sv[pass];
            uint4 v;
            if (s < stot) {
                v = rows[s * SL + c];
            } else {   // overflow: reconstruct global row (rare/never)
                int r = 0;
                while (s >= s_pfx[r + 1]) ++r;
                int row_g = s_start[r] + (s - s_pfx[r]);
                v = *(const uint4*)(q + row_g * FH + c * 8);
            }
            ax = pkmax(ax, v.x); ay = pkmax(ay, v.y);
            az = pkmax(az, v.z); aw = pkmax(aw, v.w);
        }
#pragma unroll
        for (int st = SL; st < 64; st <<= 1) {
            ax = pkmax(ax, (unsigned)__shfl_xor((int)ax, st, 64));
            ay = pkmax(ay, (unsigned)__shfl_xor((int)ay, st, 64));
            az = pkmax(az, (unsigned)__shfl_xor((int)az, st, 64));
            aw = pkmax(aw, (unsigned)__shfl_xor((int)aw, st, 64));
        }
        if (ep == 0) {
            uint4 r4; r4.x = ax; r4.y = ay; r4.z = az; r4.w = aw;
            m_lds[pl * SL + c] = r4;
        }
    }
    __syncthreads();

    // finish: agg = celu(m - G), x = celu(agg@wb + bb), emit qnext / scatter x
    for (int lt = threadIdx.x; lt < P; lt += 256) {
        int p = base + lt;
        float p0 = pos_s[3 * p + 0];
        float p1 = pos_s[3 * p + 1];
        float p2 = pos_s[3 * p + 2];

        float h[FH];
#pragma unroll
        for (int k = 0; k < SL; ++k) {
            uint4 vv = m_lds[lt * SL + k];
            unsigned w4[4] = {vv.x, vv.y, vv.z, vv.w};
#pragma unroll
            for (int kk = 0; kk < 4; ++kk) {
                float2 f = __half22float2(*(__half2*)&w4[kk]);
                h[k * 8 + kk * 2 + 0] = f.x;
                h[k * 8 + kk * 2 + 1] = f.y;
            }
        }
#pragma unroll
        for (int ch = 0; ch < FH; ++ch) {
            float gg = p0 * wap[ch] + p1 * wap[FH + ch] + p2 * wap[2 * FH + ch];
            h[ch] = celu1(h[ch] - gg);
        }
        float x[FOUT];
#pragma unroll
        for (int c2 = 0; c2 < FOUT; ++c2) {
            float a = bb[c2];
#pragma unroll
            for (int ch = 0; ch < FH; ++ch)
                a = fmaf(h[ch], wb[ch * FOUT + c2], a);
            x[c2] = celu1(a);
        }
        if constexpr (WRITEX) {
            int orig = perm[p];
            float4* xo = (float4*)(xout + (long long)orig * FOUT);
#pragma unroll
            for (int c4 = 0; c4 < FOUT / 4; ++c4)
                xo[c4] = make_float4(x[4 * c4 + 0], x[4 * c4 + 1], x[4 * c4 + 2], x[4 * c4 + 3]);
        }
        if constexpr (FHN > 0) {
            float qn[FHN];
#pragma unroll
            for (int cn = 0; cn < FHN; ++cn) {
                float a = ban[cn];
#pragma unroll
                for (int c2 = 0; c2 < FOUT; ++c2)
                    a = fmaf(x[c2], wan[c2 * FHN + cn], a);
                a = fmaf(p0, wan[(FOUT + 0) * FHN + cn], a);
                a = fmaf(p1, wan[(FOUT + 1) * FHN + cn], a);
                a = fmaf(p2, wan[(FOUT + 2) * FHN + cn], a);
                qn[cn] = a;
            }
            uint4* qo = (uint4*)(qnext + p * FHN);
#pragma unroll
            for (int k = 0; k < FHN / 8; ++k) {
                uint4 pk;
                pk.x = pack2(qn[k * 8 + 0], qn[k * 8 + 1]);
                pk.y = pack2(qn[k * 8 + 2], qn[k * 8 + 3]);
                pk.z = pack2(qn[k * 8 + 4], qn[k * 8 + 5]);
                pk.w = pack2(qn[k * 8 + 6], qn[k * 8 + 7]);
                qo[k] = pk;
            }
        }
    }
}

extern "C" void kernel_launch(void* const* d_in, const int* in_sizes, int n_in,
                              void* d_out, int out_size, void* d_ws, size_t ws_size,
                              hipStream_t stream) {
    const float* pos = (const float*)d_in[0];
    const int* idx = (const int*)d_in[4];   // in_index, int32 per harness contract
    const float* w1a = (const float*)d_in[5];
    const float* b1a = (const float*)d_in[6];
    const float* w1b = (const float*)d_in[7];
    const float* b1b = (const float*)d_in[8];
    const float* w2a = (const float*)d_in[9];
    const float* b2a = (const float*)d_in[10];
    const float* w2b = (const float*)d_in[11];
    const float* b2b = (const float*)d_in[12];
    const float* w3a = (const float*)d_in[13];
    const float* b3a = (const float*)d_in[14];
    const float* w3b = (const float*)d_in[15];
    const float* b3b = (const float*)d_in[16];
    float* out = (float*)d_out;

    char* ws = (char*)d_ws;
    unsigned short* es  = (unsigned short*)ws;                    // 8 MB
    __half* q1          = (__half*)(ws + (8u << 20));             // 1 MB
    __half* q2          = (__half*)(ws + (9u << 20));             // 2 MB
    __half* q3          = (__half*)(ws + (11u << 20));            // 4 MB
    float*  pos_s       = (float*)(ws + (15u << 20));             // 768 KB
    int*    slot_of     = (int*)(ws + (16u << 20));               // 256 KB
    int*    perm        = (int*)(ws + (16u << 20) + (256u << 10));// 256 KB
    unsigned short* c16 = (unsigned short*)(ws + (16u << 20) + (512u << 10)); // 128 KB
    int*    counts      = (int*)(ws + (17u << 20));               // 16 KB
    int*    cursor      = counts + NCELL;                         // 16 KB
    int*    starts      = cursor + NCELL;                         // 16 KB

    k_zero<<<2 * NCELL / 256, 256, 0, stream>>>(counts);
    k_hist<<<NPTS / 256, 256, 0, stream>>>(pos, counts);
    k_scan<<<1, 64, 0, stream>>>(counts, starts);
    k_slot<<<NPTS / 256, 256, 0, stream>>>(pos, starts, cursor, slot_of, perm,
                                           c16, pos_s, w1a, b1a, q1, out, out_size);
    k_remap<<<NCELL, 256, 0, stream>>>(idx, perm, slot_of, c16, starts, counts, es);

    // layer 1: FH=8 (SCAP=1024 -> 18 KB LDS, 8 blk/CU)
    k_layer<8, 8, 16, false, 1024><<<NCELL, 256, 0, stream>>>(
        q1, es, pos_s, starts, counts, perm,
        w1a + 3 * 8, w1b, b1b, w2a, b2a, nullptr, q2);
    // layer 2: FH=16 (SCAP=1024 -> 36 KB LDS, 4 blk/CU)
    k_layer<16, 16, 32, false, 1024><<<NCELL, 256, 0, stream>>>(
        q2, es, pos_s, starts, counts, perm,
        w2a + 8 * 16, w2b, b2b, w3a, b3a, nullptr, q3);
    // layer 3: FH=32 (SCAP=640 -> 48 KB LDS, 3 blk/CU)
    k_layer<32, 32, 0, true, 640><<<NCELL, 256, 0, stream>>>(
        q3, es, pos_s, starts, counts, perm,
        w3a + 16 * 32, w3b, b3b, nullptr, nullptr, out + 3 * NPTS, nullptr);
}

// Round 9
// 365.642 us; speedup vs baseline: 1.2805x; 1.2805x over previous
//
#include <hip/hip_runtime.h>
#include <hip/hip_fp16.h>
#include <math.h>

// SPAIRPointFeatureNetwork on MI355X.
//   h_{p,j} = Q[j] - G[p];  celu monotonic => segmax(celu(h)) = celu(max_j Q[j] - G[p]).
//
// R8 post-mortem: cell-LDS concept validated (FETCH 280->12 MB) but impl sank
// it: 64B LDS stride -> structural bank conflicts (3.4M); 48KB LDS x 4-wave
// blocks -> 12.7% occupancy; per-slot LDS search in staging; 2 random gathers
// per edge in remap. R9 fixes all four: padded stride (SL+1), 512-thr blocks,
// range-loop staging, packed cellslot (1 gather/edge).

#define NPTS 65536
#define KNBR 64
#define GRES 16
#define NCELL 4096   // 16^3

__device__ __forceinline__ float celu1(float x) {
    return x > 0.0f ? x : (__expf(x) - 1.0f);
}

__device__ __forceinline__ unsigned pkmax(unsigned a, unsigned b) {
    unsigned d;
    asm("v_pk_max_f16 %0, %1, %2" : "=v"(d) : "v"(a), "v"(b));
    return d;
}

__device__ __forceinline__ unsigned pack2(float a, float b) {
    __half2 h = __floats2half2_rn(a, b);
    return *(unsigned*)&h;
}

__device__ __forceinline__ int cell_of(float p0, float p1, float p2) {
    int cx = min((int)(p0 * 16.0f), 15);
    int cy = min((int)(p1 * 16.0f), 15);
    int cz = min((int)(p2 * 16.0f), 15);
    return (cx * GRES + cy) * GRES + cz;
}

// 27-neighbor descriptor for cell cid (lex order over dx,dy,dz), wave 0 only.
__device__ __forceinline__ void build_desc(
    int cid, const int* __restrict__ starts, const int* __restrict__ counts,
    int* s_start, int* s_pfx)
{
    if (threadIdx.x < 64) {
        int lane = threadIdx.x;
        int cnt = 0, st = 0;
        if (lane < 27) {
            int cx = cid >> 8, cy = (cid >> 4) & 15, cz = cid & 15;
            int dx = lane / 9 - 1, dy = (lane / 3) % 3 - 1, dz = lane % 3 - 1;
            int nx = cx + dx, ny = cy + dy, nz = cz + dz;
            bool ok = ((unsigned)nx < 16u) && ((unsigned)ny < 16u) && ((unsigned)nz < 16u);
            if (ok) {
                int nc = (((nx << 4) | ny) << 4) | nz;
                cnt = counts[nc];
                st  = starts[nc];
            }
        }
        int inc = cnt;
#pragma unroll
        for (int d = 1; d < 32; d <<= 1) {
            int u = __shfl_up(inc, d, 64);
            if (lane >= d) inc += u;
        }
        if (lane < 27) { s_start[lane] = st; s_pfx[lane] = inc - cnt; }
        if (lane == 26) s_pfx[27] = inc;
    }
}

// ---- sort pipeline ----

__global__ __launch_bounds__(256) void k_zero(int* __restrict__ buf) {
    buf[blockIdx.x * 256 + threadIdx.x] = 0;   // counts + cursor
}

__global__ __launch_bounds__(256) void k_hist(
    const float* __restrict__ pos, int* __restrict__ counts)
{
    int t = blockIdx.x * 256 + threadIdx.x;
    if (t >= NPTS) return;
    int cid = cell_of(pos[3 * t], pos[3 * t + 1], pos[3 * t + 2]);
    atomicAdd(&counts[cid], 1);
}

__global__ void k_scan(const int* __restrict__ counts, int* __restrict__ starts) {
    int lane = threadIdx.x;             // 64 lanes x 64 cells
    const int4* cp = (const int4*)counts;
    int4 c[16];
#pragma unroll
    for (int k = 0; k < 16; ++k) c[k] = cp[lane * 16 + k];
    int T = 0;
#pragma unroll
    for (int k = 0; k < 16; ++k) T += c[k].x + c[k].y + c[k].z + c[k].w;
    int inc = T;
#pragma unroll
    for (int d = 1; d < 64; d <<= 1) {
        int u = __shfl_up(inc, d, 64);
        if (lane >= d) inc += u;
    }
    int run = inc - T;
    int4* sp = (int4*)starts;
#pragma unroll
    for (int k = 0; k < 16; ++k) {
        int4 v = c[k], o;
        o.x = run; run += v.x;
        o.y = run; run += v.y;
        o.z = run; run += v.z;
        o.w = run; run += v.w;
        sp[lane * 16 + k] = o;
    }
}

// slot assignment + packed (cell<<16|slot) + sorted pos + sorted Q1 + outputs
__global__ __launch_bounds__(256) void k_slot(
    const float* __restrict__ pos,
    const int* __restrict__ starts, int* __restrict__ cursor,
    unsigned* __restrict__ cellslot, int* __restrict__ perm,
    float* __restrict__ pos_s,
    const float* __restrict__ w1a, const float* __restrict__ b1a,
    __half* __restrict__ q1,
    float* __restrict__ dout, int out_size)
{
    int t = blockIdx.x * 256 + threadIdx.x;
    if (t >= NPTS) return;
    float p0 = pos[3 * t + 0];
    float p1 = pos[3 * t + 1];
    float p2 = pos[3 * t + 2];
    dout[3 * t + 0] = p0;
    dout[3 * t + 1] = p1;
    dout[3 * t + 2] = p2;
    for (int j = 35 * NPTS + t; j < out_size; j += NPTS)
        dout[j] = 0.0f;

    int cid = cell_of(p0, p1, p2);
    int s = starts[cid] + atomicAdd(&cursor[cid], 1);
    cellslot[t] = ((unsigned)cid << 16) | (unsigned)s;
    perm[s] = t;
    pos_s[3 * s + 0] = p0;
    pos_s[3 * s + 1] = p1;
    pos_s[3 * s + 2] = p2;

    float q[8];
#pragma unroll
    for (int c = 0; c < 8; ++c) {
        float a = b1a[c];
        a = fmaf(p0, w1a[0 * 8 + c] + w1a[3 * 8 + c], a);
        a = fmaf(p1, w1a[1 * 8 + c] + w1a[4 * 8 + c], a);
        a = fmaf(p2, w1a[2 * 8 + c] + w1a[5 * 8 + c], a);
        q[c] = a;
    }
    uint4 pk;
    pk.x = pack2(q[0], q[1]);
    pk.y = pack2(q[2], q[3]);
    pk.z = pack2(q[4], q[5]);
    pk.w = pack2(q[6], q[7]);
    *(uint4*)(q1 + 8 * s) = pk;
}

// remap edges to neighborhood-local slots: ONE random gather per edge.
__global__ __launch_bounds__(256) void k_remap(
    const int* __restrict__ idx,
    const int* __restrict__ perm,
    const unsigned* __restrict__ cellslot,
    const int* __restrict__ starts,
    const int* __restrict__ counts,
    unsigned short* __restrict__ es)
{
    __shared__ int s_start[27];
    __shared__ int s_pfx[28];
    int cid = blockIdx.x;
    build_desc(cid, starts, counts, s_start, s_pfx);
    __syncthreads();

    int base = starts[cid];
    int P = counts[cid];
    int cx = cid >> 8, cy = (cid >> 4) & 15, cz = cid & 15;
    int tasks = P * 64;
    for (int task = threadIdx.x; task < tasks; task += 256) {
        int p_s = base + (task >> 6);
        int e = task & 63;
        int orig = perm[p_s];
        int j_orig = idx[orig * 64 + e];
        unsigned csj = cellslot[j_orig];
        int j_s = (int)(csj & 0xFFFFu);
        int jc  = (int)(csj >> 16);
        int r = ((jc >> 8) - cx + 1) * 9 + (((jc >> 4) & 15) - cy + 1) * 3 + ((jc & 15) - cz + 1);
        es[p_s * 64 + e] = (unsigned short)(s_pfx[r] + (j_s - s_start[r]));
    }
}

// ---- fused layer, per-cell, 512 threads ----
// Stage neighborhood rows in LDS (padded stride), edges read LDS, finish fused.
template <int FH, int FOUT, int FHN, bool WRITEX, int SCAP>
__global__ __launch_bounds__(512) void k_layer(
    const __half* __restrict__ q,    // sorted N x FH
    const unsigned short* __restrict__ es,
    const float* __restrict__ pos_s,
    const int* __restrict__ starts,
    const int* __restrict__ counts,
    const int* __restrict__ perm,
    const float* __restrict__ wap,   // 3 x FH
    const float* __restrict__ wb,    // FH x FOUT
    const float* __restrict__ bb,    // FOUT
    const float* __restrict__ wan,   // (FOUT+3) x FHN or null
    const float* __restrict__ ban,   // FHN or null
    float* __restrict__ xout,        // WRITEX only
    __half* __restrict__ qnext)      // FHN>0 only
{
    constexpr int SL = FH / 8;               // 16B slices per row (1,2,4)
    constexpr int PS = (SL == 1) ? 1 : SL + 1;   // padded stride -> ~2-way banks
    constexpr int MCAP = 96;                 // max points/cell supported

    __shared__ int s_start[27];
    __shared__ int s_pfx[28];
    __shared__ uint4 rows[SCAP * PS];
    __shared__ uint4 m_lds[MCAP * SL];

    int cid = blockIdx.x;
    build_desc(cid, starts, counts, s_start, s_pfx);
    __syncthreads();

    int stot = min(s_pfx[27], SCAP);

    // stage: 27 contiguous ranges, coalesced, search-free
    for (int r = 0; r < 27; ++r) {
        int b0 = s_pfx[r];
        int cnt = min(s_pfx[r + 1], stot) - b0;
        int st = s_start[r];
        for (int t = (int)threadIdx.x; t < cnt * SL; t += 512) {
            int row = t / SL, k = t % SL;
            rows[(b0 + row) * PS + k] = *((const uint4*)(q + (st + row) * FH) + k);
        }
    }
    __syncthreads();

    int base = starts[cid];
    int P = counts[cid];
    int w = threadIdx.x >> 6;
    int l = threadIdx.x & 63;
    int c  = l % SL;     // slice
    int ep = l / SL;     // edge group; lane covers edges [ep*SL, ep*SL+SL)

    for (int pl = w; pl < P; pl += 8) {   // one point per wave per iter
        int p = base + pl;
        unsigned short sv[SL];
        if constexpr (SL == 1) {
            sv[0] = es[p * 64 + ep];
        } else if constexpr (SL == 2) {
            unsigned raw = *(const unsigned*)(es + p * 64 + ep * 2);
            sv[0] = (unsigned short)raw;
            sv[1] = (unsigned short)(raw >> 16);
        } else {
            unsigned long long raw = *(const unsigned long long*)(es + p * 64 + ep * 4);
            sv[0] = (unsigned short)raw;
            sv[1] = (unsigned short)(raw >> 16);
            sv[2] = (unsigned short)(raw >> 32);
            sv[3] = (unsigned short)(raw >> 48);
        }
        unsigned ax = 0xFC00FC00u, ay = 0xFC00FC00u, az = 0xFC00FC00u, aw = 0xFC00FC00u;
#pragma unroll
        for (int pass = 0; pass < SL; ++pass) {
            int s = sv[pass];
            uint4 v;
            if (s < stot) {
                v = rows[s * PS + c];
            } else {   // overflow: global fallback (statistically never)
                int r = 0;
                while (s >= s_pfx[r + 1]) ++r;
                int rg = s_start[r] + (s - s_pfx[r]);
                v = *((const uint4*)(q + rg * FH) + c);
            }
            ax = pkmax(ax, v.x); ay = pkmax(ay, v.y);
            az = pkmax(az, v.z); aw = pkmax(aw, v.w);
        }
#pragma unroll
        for (int st = SL; st < 64; st <<= 1) {
            ax = pkmax(ax, (unsigned)__shfl_xor((int)ax, st, 64));
            ay = pkmax(ay, (unsigned)__shfl_xor((int)ay, st, 64));
            az = pkmax(az, (unsigned)__shfl_xor((int)az, st, 64));
            aw = pkmax(aw, (unsigned)__shfl_xor((int)aw, st, 64));
        }
        if (ep == 0 && pl < MCAP) {
            uint4 r4; r4.x = ax; r4.y = ay; r4.z = az; r4.w = aw;
            m_lds[pl * SL + c] = r4;
        }
    }
    __syncthreads();

    int PM = min(P, MCAP);
    if constexpr (!WRITEX) {
        // 1 thread per point: h = celu(m - G); x = celu(h@wb+bb); emit qnext
        for (int lt = threadIdx.x; lt < PM; lt += 512) {
            int p = base + lt;
            float p0 = pos_s[3 * p + 0];
            float p1 = pos_s[3 * p + 1];
            float p2 = pos_s[3 * p + 2];
            float h[FH];
#pragma unroll
            for (int k = 0; k < SL; ++k) {
                uint4 vv = m_lds[lt * SL + k];
                unsigned w4[4] = {vv.x, vv.y, vv.z, vv.w};
#pragma unroll
                for (int kk = 0; kk < 4; ++kk) {
                    float2 f = __half22float2(*(__half2*)&w4[kk]);
                    h[k * 8 + kk * 2 + 0] = f.x;
                    h[k * 8 + kk * 2 + 1] = f.y;
                }
            }
#pragma unroll
            for (int ch = 0; ch < FH; ++ch) {
                float gg = p0 * wap[ch] + p1 * wap[FH + ch] + p2 * wap[2 * FH + ch];
                h[ch] = celu1(h[ch] - gg);
            }
            float x[FOUT];
#pragma unroll
            for (int c2 = 0; c2 < FOUT; ++c2) {
                float a = bb[c2];
#pragma unroll
                for (int ch = 0; ch < FH; ++ch)
                    a = fmaf(h[ch], wb[ch * FOUT + c2], a);
                x[c2] = celu1(a);
            }
            float qn[FHN];
#pragma unroll
            for (int cn = 0; cn < FHN; ++cn) {
                float a = ban[cn];
#pragma unroll
                for (int c2 = 0; c2 < FOUT; ++c2)
                    a = fmaf(x[c2], wan[c2 * FHN + cn], a);
                a = fmaf(p0, wan[(FOUT + 0) * FHN + cn], a);
                a = fmaf(p1, wan[(FOUT + 1) * FHN + cn], a);
                a = fmaf(p2, wan[(FOUT + 2) * FHN + cn], a);
                qn[cn] = a;
            }
            uint4* qo = (uint4*)(qnext + p * FHN);
#pragma unroll
            for (int k = 0; k < FHN / 8; ++k) {
                uint4 pk;
                pk.x = pack2(qn[k * 8 + 0], qn[k * 8 + 1]);
                pk.y = pack2(qn[k * 8 + 2], qn[k * 8 + 3]);
                pk.z = pack2(qn[k * 8 + 4], qn[k * 8 + 5]);
                pk.w = pack2(qn[k * 8 + 6], qn[k * 8 + 7]);
                qo[k] = pk;
            }
        }
    } else {
        // channel-split: 4 threads/point, thread j does x channels [j*8,j*8+8)
        for (int tq = threadIdx.x; tq < PM * 4; tq += 512) {
            int lt = tq >> 2, j = tq & 3;
            int p = base + lt;
            float p0 = pos_s[3 * p + 0];
            float p1 = pos_s[3 * p + 1];
            float p2 = pos_s[3 * p + 2];
            float h[FH];
#pragma unroll
            for (int k = 0; k < SL; ++k) {
                uint4 vv = m_lds[lt * SL + k];
                unsigned w4[4] = {vv.x, vv.y, vv.z, vv.w};
#pragma unroll
                for (int kk = 0; kk < 4; ++kk) {
                    float2 f = __half22float2(*(__half2*)&w4[kk]);
                    h[k * 8 + kk * 2 + 0] = f.x;
                    h[k * 8 + kk * 2 + 1] = f.y;
                }
            }
#pragma unroll
            for (int ch = 0; ch < FH; ++ch) {
                float gg = p0 * wap[ch] + p1 * wap[FH + ch] + p2 * wap[2 * FH + ch];
                h[ch] = celu1(h[ch] - gg);
            }
            float x8[8];
#pragma unroll
            for (int jj = 0; jj < 8; ++jj) {
                int c2 = j * 8 + jj;
                float a = bb[c2];
#pragma unroll
                for (int ch = 0; ch < FH; ++ch)
                    a = fmaf(h[ch], wb[ch * FOUT + c2], a);
                x8[jj] = celu1(a);
            }
            int orig = perm[p];
            float4* xo = (float4*)(xout + (long long)orig * FOUT + j * 8);
            xo[0] = make_float4(x8[0], x8[1], x8[2], x8[3]);
            xo[1] = make_float4(x8[4], x8[5], x8[6], x8[7]);
        }
    }
}

extern "C" void kernel_launch(void* const* d_in, const int* in_sizes, int n_in,
                              void* d_out, int out_size, void* d_ws, size_t ws_size,
                              hipStream_t stream) {
    const float* pos = (const float*)d_in[0];
    const int* idx = (const int*)d_in[4];   // in_index, int32 per harness contract
    const float* w1a = (const float*)d_in[5];
    const float* b1a = (const float*)d_in[6];
    const float* w1b = (const float*)d_in[7];
    const float* b1b = (const float*)d_in[8];
    const float* w2a = (const float*)d_in[9];
    const float* b2a = (const float*)d_in[10];
    const float* w2b = (const float*)d_in[11];
    const float* b2b = (const float*)d_in[12];
    const float* w3a = (const float*)d_in[13];
    const float* b3a = (const float*)d_in[14];
    const float* w3b = (const float*)d_in[15];
    const float* b3b = (const float*)d_in[16];
    float* out = (float*)d_out;

    char* ws = (char*)d_ws;
    unsigned short* es = (unsigned short*)ws;                     // 8 MB
    __half* q1         = (__half*)(ws + (8u << 20));              // 1 MB
    __half* q2         = (__half*)(ws + (9u << 20));              // 2 MB
    __half* q3         = (__half*)(ws + (11u << 20));             // 4 MB
    float*  pos_s      = (float*)(ws + (15u << 20));              // 768 KB
    unsigned* cellslot = (unsigned*)(ws + (16u << 20));           // 256 KB
    int*    perm       = (int*)(ws + (16u << 20) + (256u << 10)); // 256 KB
    int*    counts     = (int*)(ws + (17u << 20));                // 16 KB
    int*    cursor     = counts + NCELL;                          // 16 KB
    int*    starts     = cursor + NCELL;                          // 16 KB

    k_zero<<<2 * NCELL / 256, 256, 0, stream>>>(counts);
    k_hist<<<NPTS / 256, 256, 0, stream>>>(pos, counts);
    k_scan<<<1, 64, 0, stream>>>(counts, starts);
    k_slot<<<NPTS / 256, 256, 0, stream>>>(pos, starts, cursor, cellslot, perm,
                                           pos_s, w1a, b1a, q1, out, out_size);
    k_remap<<<NCELL, 256, 0, stream>>>(idx, perm, cellslot, starts, counts, es);

    // layer 1: FH=8  (rows 16 KB + m 1.5 KB -> ~8 blk/CU)
    k_layer<8, 8, 16, false, 1024><<<NCELL, 512, 0, stream>>>(
        q1, es, pos_s, starts, counts, perm,
        w1a + 3 * 8, w1b, b1b, w2a, b2a, nullptr, q2);
    // layer 2: FH=16 (rows 27.6 KB + m 3 KB -> ~5 blk/CU)
    k_layer<16, 16, 32, false, 576><<<NCELL, 512, 0, stream>>>(
        q2, es, pos_s, starts, counts, perm,
        w2a + 8 * 16, w2b, b2b, w3a, b3a, nullptr, q3);
    // layer 3: FH=32 (rows 43.5 KB + m 6 KB -> 3 blk/CU)
    k_layer<32, 32, 0, true, 544><<<NCELL, 512, 0, stream>>>(
        q3, es, pos_s, starts, counts, perm,
        w3a + 16 * 32, w3b, b3b, nullptr, nullptr, out + 3 * NPTS, nullptr);
}

// Round 10
// 251.920 us; speedup vs baseline: 1.8585x; 1.4514x over previous
//
#include <hip/hip_runtime.h>
#include <hip/hip_fp16.h>
#include <math.h>

// SPAIRPointFeatureNetwork on MI355X.
//   h_{p,j} = Q[j] - G[p];  celu monotonic => segmax(celu(h)) = celu(max_j Q[j] - G[p]).
//
// R9 post-mortem: per-block critical path ~45K cyc — staging ran 27 serialized
// load->wait->ds_write rounds and es loads sat in the edge dependency chain.
// R10: row_src slot table built by wave0 (LDS-only) -> flat staging loop of
// independent loads; es software-pipelined across rounds; 16 lanes/point.

#define NPTS 65536
#define KNBR 64
#define GRES 16
#define NCELL 4096   // 16^3

__device__ __forceinline__ float celu1(float x) {
    return x > 0.0f ? x : (__expf(x) - 1.0f);
}

__device__ __forceinline__ unsigned pkmax(unsigned a, unsigned b) {
    unsigned d;
    asm("v_pk_max_f16 %0, %1, %2" : "=v"(d) : "v"(a), "v"(b));
    return d;
}

__device__ __forceinline__ unsigned pack2(float a, float b) {
    __half2 h = __floats2half2_rn(a, b);
    return *(unsigned*)&h;
}

__device__ __forceinline__ int cell_of(float p0, float p1, float p2) {
    int cx = min((int)(p0 * 16.0f), 15);
    int cy = min((int)(p1 * 16.0f), 15);
    int cz = min((int)(p2 * 16.0f), 15);
    return (cx * GRES + cy) * GRES + cz;
}

// ---- sort pipeline ----

__global__ __launch_bounds__(256) void k_zero(int* __restrict__ buf) {
    buf[blockIdx.x * 256 + threadIdx.x] = 0;   // counts + cursor
}

__global__ __launch_bounds__(256) void k_hist(
    const float* __restrict__ pos, int* __restrict__ counts)
{
    int t = blockIdx.x * 256 + threadIdx.x;
    if (t >= NPTS) return;
    int cid = cell_of(pos[3 * t], pos[3 * t + 1], pos[3 * t + 2]);
    atomicAdd(&counts[cid], 1);
}

__global__ void k_scan(const int* __restrict__ counts, int* __restrict__ starts) {
    int lane = threadIdx.x;             // 64 lanes x 64 cells
    const int4* cp = (const int4*)counts;
    int4 c[16];
#pragma unroll
    for (int k = 0; k < 16; ++k) c[k] = cp[lane * 16 + k];
    int T = 0;
#pragma unroll
    for (int k = 0; k < 16; ++k) T += c[k].x + c[k].y + c[k].z + c[k].w;
    int inc = T;
#pragma unroll
    for (int d = 1; d < 64; d <<= 1) {
        int u = __shfl_up(inc, d, 64);
        if (lane >= d) inc += u;
    }
    int run = inc - T;
    int4* sp = (int4*)starts;
#pragma unroll
    for (int k = 0; k < 16; ++k) {
        int4 v = c[k], o;
        o.x = run; run += v.x;
        o.y = run; run += v.y;
        o.z = run; run += v.z;
        o.w = run; run += v.w;
        sp[lane * 16 + k] = o;
    }
}

__global__ __launch_bounds__(256) void k_slot(
    const float* __restrict__ pos,
    const int* __restrict__ starts, int* __restrict__ cursor,
    unsigned* __restrict__ cellslot, int* __restrict__ perm,
    float* __restrict__ pos_s,
    const float* __restrict__ w1a, const float* __restrict__ b1a,
    __half* __restrict__ q1,
    float* __restrict__ dout, int out_size)
{
    int t = blockIdx.x * 256 + threadIdx.x;
    if (t >= NPTS) return;
    float p0 = pos[3 * t + 0];
    float p1 = pos[3 * t + 1];
    float p2 = pos[3 * t + 2];
    dout[3 * t + 0] = p0;
    dout[3 * t + 1] = p1;
    dout[3 * t + 2] = p2;
    for (int j = 35 * NPTS + t; j < out_size; j += NPTS)
        dout[j] = 0.0f;

    int cid = cell_of(p0, p1, p2);
    int s = starts[cid] + atomicAdd(&cursor[cid], 1);
    cellslot[t] = ((unsigned)cid << 16) | (unsigned)s;
    perm[s] = t;
    pos_s[3 * s + 0] = p0;
    pos_s[3 * s + 1] = p1;
    pos_s[3 * s + 2] = p2;

    float q[8];
#pragma unroll
    for (int c = 0; c < 8; ++c) {
        float a = b1a[c];
        a = fmaf(p0, w1a[0 * 8 + c] + w1a[3 * 8 + c], a);
        a = fmaf(p1, w1a[1 * 8 + c] + w1a[4 * 8 + c], a);
        a = fmaf(p2, w1a[2 * 8 + c] + w1a[5 * 8 + c], a);
        q[c] = a;
    }
    uint4 pk;
    pk.x = pack2(q[0], q[1]);
    pk.y = pack2(q[2], q[3]);
    pk.z = pack2(q[4], q[5]);
    pk.w = pack2(q[6], q[7]);
    *(uint4*)(q1 + 8 * s) = pk;
}

// remap edges to neighborhood-local slots: one random 4B gather per edge.
__global__ __launch_bounds__(256) void k_remap(
    const int* __restrict__ idx,
    const int* __restrict__ perm,
    const unsigned* __restrict__ cellslot,
    const int* __restrict__ starts,
    const int* __restrict__ counts,
    unsigned short* __restrict__ es)
{
    __shared__ int s_start[27];
    __shared__ int s_pfx[28];
    int cid = blockIdx.x;
    if (threadIdx.x < 64) {
        int lane = threadIdx.x;
        int cnt = 0, st = 0;
        if (lane < 27) {
            int cx = cid >> 8, cy = (cid >> 4) & 15, cz = cid & 15;
            int dx = lane / 9 - 1, dy = (lane / 3) % 3 - 1, dz = lane % 3 - 1;
            int nx = cx + dx, ny = cy + dy, nz = cz + dz;
            bool ok = ((unsigned)nx < 16u) && ((unsigned)ny < 16u) && ((unsigned)nz < 16u);
            if (ok) {
                int nc = (((nx << 4) | ny) << 4) | nz;
                cnt = counts[nc];
                st  = starts[nc];
            }
        }
        int inc = cnt;
#pragma unroll
        for (int d = 1; d < 32; d <<= 1) {
            int u = __shfl_up(inc, d, 64);
            if (lane >= d) inc += u;
        }
        if (lane < 27) { s_start[lane] = st; s_pfx[lane] = inc - cnt; }
        if (lane == 26) s_pfx[27] = inc;
    }
    __syncthreads();

    int base = starts[cid];
    int P = counts[cid];
    int cx = cid >> 8, cy = (cid >> 4) & 15, cz = cid & 15;
    int tasks = P * 64;
    for (int task = threadIdx.x; task < tasks; task += 256) {
        int p_s = base + (task >> 6);
        int e = task & 63;
        int orig = perm[p_s];
        int j_orig = idx[orig * 64 + e];
        unsigned csj = cellslot[j_orig];
        int j_s = (int)(csj & 0xFFFFu);
        int jc  = (int)(csj >> 16);
        int r = ((jc >> 8) - cx + 1) * 9 + (((jc >> 4) & 15) - cy + 1) * 3 + ((jc & 15) - cz + 1);
        es[p_s * 64 + e] = (unsigned short)(s_pfx[r] + (j_s - s_start[r]));
    }
}

// ---- fused layer, per-cell, 512 threads, pipelined ----
template <int FH, int FOUT, int FHN, bool WRITEX, int SCAP>
__global__ __launch_bounds__(512, 6) void k_layer(
    const __half* __restrict__ q,    // sorted N x FH
    const unsigned short* __restrict__ es,
    const float* __restrict__ pos_s,
    const int* __restrict__ starts,
    const int* __restrict__ counts,
    const int* __restrict__ perm,
    const float* __restrict__ wap,   // 3 x FH
    const float* __restrict__ wb,    // FH x FOUT
    const float* __restrict__ bb,    // FOUT
    const float* __restrict__ wan,   // (FOUT+3) x FHN or null
    const float* __restrict__ ban,   // FHN or null
    float* __restrict__ xout,        // WRITEX only
    __half* __restrict__ qnext)      // FHN>0 only
{
    constexpr int SL   = FH / 8;                 // 16B slices per row (1,2,4)
    constexpr int PS   = (SL == 1) ? 1 : SL + 1; // padded LDS stride (uint4s)
    constexpr int MCAP = 96;                     // max points/cell
    constexpr int EPL  = 4 * SL;                 // edges per lane (4,8,16)
    constexpr int ER   = EPL / 2;                // packed u32 regs of es

    __shared__ int s_start[27];
    __shared__ int s_pfx[28];
    __shared__ int row_src[SCAP];
    __shared__ uint4 rows[SCAP * PS];
    __shared__ uint4 m_lds[MCAP * SL];

    int cid = blockIdx.x;
    int base = starts[cid];    // uniform scalar loads
    int P    = counts[cid];

    // ---- phase A (pre-barrier): wave0 builds desc + row_src; all prefetch es
    if (threadIdx.x < 64) {
        int lane = threadIdx.x;
        int cnt = 0, st = 0;
        if (lane < 27) {
            int cx = cid >> 8, cy = (cid >> 4) & 15, cz = cid & 15;
            int dx = lane / 9 - 1, dy = (lane / 3) % 3 - 1, dz = lane % 3 - 1;
            int nx = cx + dx, ny = cy + dy, nz = cz + dz;
            bool ok = ((unsigned)nx < 16u) && ((unsigned)ny < 16u) && ((unsigned)nz < 16u);
            if (ok) {
                int nc = (((nx << 4) | ny) << 4) | nz;
                cnt = counts[nc];
                st  = starts[nc];
            }
        }
        int inc = cnt;
#pragma unroll
        for (int d = 1; d < 32; d <<= 1) {
            int u = __shfl_up(inc, d, 64);
            if (lane >= d) inc += u;
        }
        if (lane < 27) {
            int b0 = inc - cnt;
            s_start[lane] = st;
            s_pfx[lane]   = b0;
            for (int k = 0; k < cnt; ++k)    // LDS-only, 27 lanes in parallel
                if (b0 + k < SCAP) row_src[b0 + k] = st + k;
        }
        if (lane == 26) s_pfx[27] = inc;
    }

    int w    = threadIdx.x >> 6;
    int lane = threadIdx.x & 63;
    int u    = lane & 15;
    int c    = u % SL;          // slice
    int g    = u / SL;          // edge group (16/SL groups x EPL edges)
    int pl   = w * 4 + (lane >> 4);

    unsigned er[ER];
    if (pl < P) {               // prefetch round-0 es (global, no LDS dep)
        const unsigned* ep = (const unsigned*)(es + (long long)(base + pl) * 64 + g * EPL);
        if constexpr (EPL == 4) {
            uint2 t = *(const uint2*)ep; er[0] = t.x; er[1] = t.y;
        } else if constexpr (EPL == 8) {
            uint4 t = *(const uint4*)ep;
            er[0] = t.x; er[1] = t.y; er[2] = t.z; er[3] = t.w;
        } else {
            uint4 t0 = ((const uint4*)ep)[0], t1 = ((const uint4*)ep)[1];
            er[0] = t0.x; er[1] = t0.y; er[2] = t0.z; er[3] = t0.w;
            er[4] = t1.x; er[5] = t1.y; er[6] = t1.z; er[7] = t1.w;
        }
    }
    __syncthreads();

    // ---- phase B: flat staging, all loads independent
    int stot = min(s_pfx[27], SCAP);
    for (int t = threadIdx.x; t < stot * SL; t += 512) {
        int row = t / SL;
        int sl  = t % SL;
        int src = row_src[row];
        rows[row * PS + sl] = *((const uint4*)(q + (long long)src * FH) + sl);
    }
    __syncthreads();

    // ---- phase C: edge max, es pipelined across rounds
    for (; pl < P; pl += 32) {
        unsigned ax = 0xFC00FC00u, ay = 0xFC00FC00u, az = 0xFC00FC00u, aw = 0xFC00FC00u;
#pragma unroll
        for (int k0 = 0; k0 < EPL; k0 += 8) {
            constexpr int CH = (EPL < 8) ? EPL : 8;
            uint4 v[CH];
#pragma unroll
            for (int k = 0; k < CH; ++k) {
                int kk = k0 + k;
                int s = (int)((er[kk >> 1] >> ((kk & 1) * 16)) & 0xFFFFu);
                if (s < stot) {
                    v[k] = rows[s * PS + c];
                } else {       // overflow fallback (statistically never)
                    int r = 0;
                    while (s >= s_pfx[r + 1]) ++r;
                    int rg = s_start[r] + (s - s_pfx[r]);
                    v[k] = *((const uint4*)(q + (long long)rg * FH) + c);
                }
            }
#pragma unroll
            for (int k = 0; k < CH; ++k) {
                ax = pkmax(ax, v[k].x); ay = pkmax(ay, v[k].y);
                az = pkmax(az, v[k].z); aw = pkmax(aw, v[k].w);
            }
        }
        // prefetch next round's es before the shuffle chain
        int nl = pl + 32;
        if (nl < P) {
            const unsigned* ep = (const unsigned*)(es + (long long)(base + nl) * 64 + g * EPL);
            if constexpr (EPL == 4) {
                uint2 t = *(const uint2*)ep; er[0] = t.x; er[1] = t.y;
            } else if constexpr (EPL == 8) {
                uint4 t = *(const uint4*)ep;
                er[0] = t.x; er[1] = t.y; er[2] = t.z; er[3] = t.w;
            } else {
                uint4 t0 = ((const uint4*)ep)[0], t1 = ((const uint4*)ep)[1];
                er[0] = t0.x; er[1] = t0.y; er[2] = t0.z; er[3] = t0.w;
                er[4] = t1.x; er[5] = t1.y; er[6] = t1.z; er[7] = t1.w;
            }
        }
        // butterfly across edge groups (strides SL..8 stay inside 16-lane point)
#pragma unroll
        for (int st = SL; st < 16; st <<= 1) {
            ax = pkmax(ax, (unsigned)__shfl_xor((int)ax, st, 64));
            ay = pkmax(ay, (unsigned)__shfl_xor((int)ay, st, 64));
            az = pkmax(az, (unsigned)__shfl_xor((int)az, st, 64));
            aw = pkmax(aw, (unsigned)__shfl_xor((int)aw, st, 64));
        }
        if (g == 0 && pl < MCAP) {
            uint4 r4; r4.x = ax; r4.y = ay; r4.z = az; r4.w = aw;
            m_lds[pl * SL + c] = r4;
        }
    }
    __syncthreads();

    // ---- phase D: finish
    int PM = min(P, MCAP);
    if constexpr (!WRITEX) {
        for (int lt = threadIdx.x; lt < PM; lt += 512) {
            int p = base + lt;
            float p0 = pos_s[3 * p + 0];
            float p1 = pos_s[3 * p + 1];
            float p2 = pos_s[3 * p + 2];
            float h[FH];
#pragma unroll
            for (int k = 0; k < SL; ++k) {
                uint4 vv = m_lds[lt * SL + k];
                unsigned w4[4] = {vv.x, vv.y, vv.z, vv.w};
#pragma unroll
                for (int kk = 0; kk < 4; ++kk) {
                    float2 f = __half22float2(*(__half2*)&w4[kk]);
                    h[k * 8 + kk * 2 + 0] = f.x;
                    h[k * 8 + kk * 2 + 1] = f.y;
                }
            }
#pragma unroll
            for (int ch = 0; ch < FH; ++ch) {
                float gg = p0 * wap[ch] + p1 * wap[FH + ch] + p2 * wap[2 * FH + ch];
                h[ch] = celu1(h[ch] - gg);
            }
            float x[FOUT];
#pragma unroll
            for (int c2 = 0; c2 < FOUT; ++c2) {
                float a = bb[c2];
#pragma unroll
                for (int ch = 0; ch < FH; ++ch)
                    a = fmaf(h[ch], wb[ch * FOUT + c2], a);
                x[c2] = celu1(a);
            }
            uint4* qo = (uint4*)(qnext + (long long)p * FHN);
#pragma unroll
            for (int k = 0; k < FHN / 8; ++k) {   // chunked: 8 accs live at a time
                float qn[8];
#pragma unroll
                for (int j = 0; j < 8; ++j) {
                    int cn = k * 8 + j;
                    float a = ban[cn];
#pragma unroll
                    for (int c2 = 0; c2 < FOUT; ++c2)
                        a = fmaf(x[c2], wan[c2 * FHN + cn], a);
                    a = fmaf(p0, wan[(FOUT + 0) * FHN + cn], a);
                    a = fmaf(p1, wan[(FOUT + 1) * FHN + cn], a);
                    a = fmaf(p2, wan[(FOUT + 2) * FHN + cn], a);
                    qn[j] = a;
                }
                uint4 pk;
                pk.x = pack2(qn[0], qn[1]);
                pk.y = pack2(qn[2], qn[3]);
                pk.z = pack2(qn[4], qn[5]);
                pk.w = pack2(qn[6], qn[7]);
                qo[k] = pk;
            }
        }
    } else {
        // channel-split: 4 threads/point, thread j does channels [j*8, j*8+8)
        for (int tq = threadIdx.x; tq < PM * 4; tq += 512) {
            int lt = tq >> 2, j = tq & 3;
            int p = base + lt;
            float p0 = pos_s[3 * p + 0];
            float p1 = pos_s[3 * p + 1];
            float p2 = pos_s[3 * p + 2];
            float h[FH];
#pragma unroll
            for (int k = 0; k < SL; ++k) {
                uint4 vv = m_lds[lt * SL + k];
                unsigned w4[4] = {vv.x, vv.y, vv.z, vv.w};
#pragma unroll
                for (int kk = 0; kk < 4; ++kk) {
                    float2 f = __half22float2(*(__half2*)&w4[kk]);
                    h[k * 8 + kk * 2 + 0] = f.x;
                    h[k * 8 + kk * 2 + 1] = f.y;
                }
            }
#pragma unroll
            for (int ch = 0; ch < FH; ++ch) {
                float gg = p0 * wap[ch] + p1 * wap[FH + ch] + p2 * wap[2 * FH + ch];
                h[ch] = celu1(h[ch] - gg);
            }
            float x8[8];
#pragma unroll
            for (int jj = 0; jj < 8; ++jj) {
                int c2 = j * 8 + jj;
                float a = bb[c2];
#pragma unroll
                for (int ch = 0; ch < FH; ++ch)
                    a = fmaf(h[ch], wb[ch * FOUT + c2], a);
                x8[jj] = celu1(a);
            }
            int orig = perm[p];
            float4* xo = (float4*)(xout + (long long)orig * FOUT + j * 8);
            xo[0] = make_float4(x8[0], x8[1], x8[2], x8[3]);
            xo[1] = make_float4(x8[4], x8[5], x8[6], x8[7]);
        }
    }
}

extern "C" void kernel_launch(void* const* d_in, const int* in_sizes, int n_in,
                              void* d_out, int out_size, void* d_ws, size_t ws_size,
                              hipStream_t stream) {
    const float* pos = (const float*)d_in[0];
    const int* idx = (const int*)d_in[4];   // in_index, int32 per harness contract
    const float* w1a = (const float*)d_in[5];
    const float* b1a = (const float*)d_in[6];
    const float* w1b = (const float*)d_in[7];
    const float* b1b = (const float*)d_in[8];
    const float* w2a = (const float*)d_in[9];
    const float* b2a = (const float*)d_in[10];
    const float* w2b = (const float*)d_in[11];
    const float* b2b = (const float*)d_in[12];
    const float* w3a = (const float*)d_in[13];
    const float* b3a = (const float*)d_in[14];
    const float* w3b = (const float*)d_in[15];
    const float* b3b = (const float*)d_in[16];
    float* out = (float*)d_out;

    char* ws = (char*)d_ws;
    unsigned short* es = (unsigned short*)ws;                     // 8 MB
    __half* q1         = (__half*)(ws + (8u << 20));              // 1 MB
    __half* q2         = (__half*)(ws + (9u << 20));              // 2 MB
    __half* q3         = (__half*)(ws + (11u << 20));             // 4 MB
    float*  pos_s      = (float*)(ws + (15u << 20));              // 768 KB
    unsigned* cellslot = (unsigned*)(ws + (16u << 20));           // 256 KB
    int*    perm       = (int*)(ws + (16u << 20) + (256u << 10)); // 256 KB
    int*    counts     = (int*)(ws + (17u << 20));                // 16 KB
    int*    cursor     = counts + NCELL;                          // 16 KB
    int*    starts     = cursor + NCELL;                          // 16 KB

    k_zero<<<2 * NCELL / 256, 256, 0, stream>>>(counts);
    k_hist<<<NPTS / 256, 256, 0, stream>>>(pos, counts);
    k_scan<<<1, 64, 0, stream>>>(counts, starts);
    k_slot<<<NPTS / 256, 256, 0, stream>>>(pos, starts, cursor, cellslot, perm,
                                           pos_s, w1a, b1a, q1, out, out_size);
    k_remap<<<NCELL, 256, 0, stream>>>(idx, perm, cellslot, starts, counts, es);

    // layer 1: FH=8  (LDS ~22 KB, wave-capped 4 blk/CU)
    k_layer<8, 8, 16, false, 1024><<<NCELL, 512, 0, stream>>>(
        q1, es, pos_s, starts, counts, perm,
        w1a + 3 * 8, w1b, b1b, w2a, b2a, nullptr, q2);
    // layer 2: FH=16 (LDS ~31.6 KB, 4 blk/CU)
    k_layer<16, 16, 32, false, 544><<<NCELL, 512, 0, stream>>>(
        q2, es, pos_s, starts, counts, perm,
        w2a + 8 * 16, w2b, b2b, w3a, b3a, nullptr, q3);
    // layer 3: FH=32 (LDS ~52 KB, 3 blk/CU)
    k_layer<32, 32, 0, true, 544><<<NCELL, 512, 0, stream>>>(
        q3, es, pos_s, starts, counts, perm,
        w3a + 16 * 32, w3b, b3b, nullptr, nullptr, out + 3 * NPTS, nullptr);
}